// Round 6
// baseline (454.167 us; speedup 1.0000x reference)
//
#include <hip/hip_runtime.h>
#include <hip/hip_bf16.h>

#define B_ROWS 8192
#define D_DIM  256
#define QB     64
#define KB     64
#define NT     (B_ROWS / KB)
#define NT2    (NT / 2)
#define ALPHA  0.8f
// TAU * log2(e) = 3.0 * 1.4426950408889634
#define TAU_LOG2E 4.328085122666890f

typedef __attribute__((ext_vector_type(8))) short bf16x8;
typedef __attribute__((ext_vector_type(4))) float f32x4;
typedef __attribute__((ext_vector_type(4))) unsigned short ushort4v;

__device__ inline unsigned short f2bf(float f) {
    unsigned int u = __builtin_bit_cast(unsigned int, f);
    u += 0x7FFF + ((u >> 16) & 1);   // RNE (finite values)
    return (unsigned short)(u >> 16);
}

// global -> LDS DMA, 16B per lane. LDS dest = wave-uniform base + lane*16
// (linear); the swizzle is applied to the per-lane GLOBAL source instead.
__device__ inline void gl_lds16(const void* g, void* l) {
    __builtin_amdgcn_global_load_lds(
        (const __attribute__((address_space(1))) unsigned int*)g,
        (__attribute__((address_space(3))) unsigned int*)l, 16, 0, 0);
}

// raw barrier that drains only LDS ops (DMA prefetch stays in flight)
__device__ inline void barrier_lgkm() {
    asm volatile("s_waitcnt lgkmcnt(0)" ::: "memory");
    __builtin_amdgcn_s_barrier();
    asm volatile("" ::: "memory");
}
// barrier: staging DMAs + LDS ops complete
__device__ inline void barrier_all() {
    asm volatile("s_waitcnt vmcnt(0) lgkmcnt(0)" ::: "memory");
    __builtin_amdgcn_s_barrier();
    asm volatile("" ::: "memory");
}

// ---------------- Kernel A: gather + row-normalize, emit f32 + bf16 copies --
__global__ __launch_bounds__(256) void k_gather_norm(
    const float* __restrict__ ue, const float* __restrict__ ie,
    const int* __restrict__ u, const int* __restrict__ p,
    float* __restrict__ Xf, unsigned short* __restrict__ Xh,
    float* __restrict__ out)
{
    const int b = blockIdx.x * 4 + (threadIdx.x >> 6);   // 0..16383
    const int lane = threadIdx.x & 63;
    if (b == 0 && lane == 0) out[0] = 0.0f;   // init accumulator (d_out is poisoned)
    const int m = b >> 13;
    const int r = b & 8191;
    const float* src = (m == 0) ? (ue + (size_t)u[r] * D_DIM)
                                : (ie + (size_t)p[r] * D_DIM);
    float4 v = ((const float4*)src)[lane];
    float ss = v.x*v.x + v.y*v.y + v.z*v.z + v.w*v.w;
    #pragma unroll
    for (int mask = 32; mask; mask >>= 1) ss += __shfl_xor(ss, mask);
    const float inv = 1.0f / sqrtf(ss);
    v.x *= inv; v.y *= inv; v.z *= inv; v.w *= inv;
    const size_t off = (size_t)(m * B_ROWS + r) * D_DIM + lane * 4;
    *(float4*)(Xf + off) = v;
    ushort4v h = { f2bf(v.x), f2bf(v.y), f2bf(v.z), f2bf(v.w) };
    *(ushort4v*)(Xh + off) = h;
}

// ---------------- Kernel T: bf16 transpose [2][8192][256] -> [2][256][8192] --
__global__ __launch_bounds__(256) void k_transpose(
    const unsigned short* __restrict__ Xh, unsigned short* __restrict__ Xht)
{
    __shared__ unsigned short tile[64 * 84];
    const int bid = blockIdx.x;                // 0..1023
    const int m = bid >> 9;
    const int t = bid & 511;
    const int rt = t >> 2, ct = t & 3;
    const int r0 = rt * 64, c0 = ct * 64;
    const int tid = threadIdx.x;
    const unsigned short* src = Xh + (size_t)m * B_ROWS * D_DIM;
    unsigned short* dst = Xht + (size_t)m * D_DIM * B_ROWS;
    #pragma unroll
    for (int ph = 0; ph < 2; ++ph) {
        const int row = ph * 32 + (tid >> 3);
        const int ch = tid & 7;
        const unsigned short* s = src + (size_t)(r0 + row) * D_DIM + c0 + ch * 8;
        ushort4v a = *(const ushort4v*)s;
        ushort4v b = *(const ushort4v*)(s + 4);
        *(ushort4v*)(&tile[row * 84 + ch * 8]) = a;
        *(ushort4v*)(&tile[row * 84 + ch * 8 + 4]) = b;
    }
    __syncthreads();
    #pragma unroll
    for (int ph = 0; ph < 2; ++ph) {
        const int d = ph * 32 + (tid >> 3);
        const int kc = tid & 7;
        ushort4v lo = { tile[(kc*8+0)*84 + d], tile[(kc*8+1)*84 + d],
                        tile[(kc*8+2)*84 + d], tile[(kc*8+3)*84 + d] };
        ushort4v hi = { tile[(kc*8+4)*84 + d], tile[(kc*8+5)*84 + d],
                        tile[(kc*8+6)*84 + d], tile[(kc*8+7)*84 + d] };
        unsigned short* o = dst + (size_t)(c0 + d) * B_ROWS + r0 + kc * 8;
        *(ushort4v*)o = lo;
        *(ushort4v*)(o + 4) = hi;
    }
}

// ============ NEW PATH: kv-split partial flash (2 blocks/CU) =================
// grid = 512 blocks: blockIdx.x = m*256 + qb*2 + h  (qb 0..127, h 0..1)
// Each block: Q-tile 64 rows, kv range [h*4096, h*4096+4096), 64 iters.
// Single-buffered LDS (73KB) -> 2 blocks/CU; DMA latency hidden by co-block.
// Outputs: Opart[blk][64][256] f32, lsum_part[blk][64] f32.
__global__ __launch_bounds__(512, 2) void k_flash_part(
    const unsigned short* __restrict__ Xh,   // [2][8192][256] bf16
    const unsigned short* __restrict__ Xht,  // [2][256][8192] bf16
    float* __restrict__ Opart,               // [512][64][256] f32
    float* __restrict__ lsum_part)           // [512][64] f32
{
    __shared__ unsigned char Kls[64 * 512];    // 32KB, 16B-XOR-swizzled rows
    __shared__ unsigned char Vtls[256 * 128];  // 32KB: d-major, 64 kv per row
    __shared__ unsigned char Pls[64 * 128];    // 8KB
    __shared__ float lsum_sh[4][QB];

    const int tid = threadIdx.x;
    const int lane = tid & 63;
    const int w = tid >> 6;
    const int wm = w >> 2;            // 0..1: q-row group (32 rows)
    const int wn = w & 3;             // 0..3: QK col-group / PV d-group
    const int m  = blockIdx.x >> 8;
    const int qb = (blockIdx.x >> 1) & 127;
    const int h  = blockIdx.x & 1;
    const int q0 = qb * QB;
    const int kvbase = h * (B_ROWS / 2);

    const unsigned short* Xm  = Xh  + (size_t)m * B_ROWS * D_DIM;
    const unsigned short* Xtm = Xht + (size_t)m * D_DIM * B_ROWS;

    // ---- Q fragments in registers -------------------------------------------
    bf16x8 qf[2][8];
    #pragma unroll
    for (int mi = 0; mi < 2; ++mi) {
        const unsigned short* qbp = Xm + (size_t)(q0 + wm*32 + mi*16 + (lane & 15)) * D_DIM
                                       + (lane >> 4) * 8;
        #pragma unroll
        for (int kk = 0; kk < 8; ++kk)
            qf[mi][kk] = *(const bf16x8*)(qbp + kk * 32);
    }

    // ---- DMA staging geometry (identical swizzle to proven r4 kernel) ------
    const int kchunk0 = w * 4;
    const int krow_l  = (lane >> 5);
    const int kcol16  = lane & 31;
    const int vd_l    = (lane >> 3);
    const int vkc16   = lane & 7;

    // prologue: stage tile 0
    #pragma unroll
    for (int it = 0; it < 4; ++it) {
        const int chunk = kchunk0 + it;
        const int krow = chunk * 2 + krow_l;
        const int kdch = kcol16 ^ (krow & 7);
        gl_lds16(Xm + (size_t)(kvbase + krow) * D_DIM + kdch * 8, &Kls[chunk * 1024]);
        const int vd = chunk * 8 + vd_l;
        const int vkc = vkc16 ^ (vd & 7);
        gl_lds16(Xtm + (size_t)vd * B_ROWS + kvbase + vkc * 8, &Vtls[chunk * 1024]);
    }

    f32x4 o[2][4];
    #pragma unroll
    for (int mi = 0; mi < 2; ++mi)
        #pragma unroll
        for (int nf = 0; nf < 4; ++nf) o[mi][nf] = (f32x4){0.f, 0.f, 0.f, 0.f};
    float lsum[2][4] = {{0.f,0.f,0.f,0.f},{0.f,0.f,0.f,0.f}};

    for (int kt = 0; kt < NT2; ++kt) {
        barrier_all();    // tile kt landed in LDS (single buffer)

        // ---- QK^T: S[32 x 16] per wave --------------------------------------
        f32x4 s0 = {0.f,0.f,0.f,0.f}, s1 = {0.f,0.f,0.f,0.f};
        {
            const int brow = wn * 16 + (lane & 15);
            const unsigned char* kbase = &Kls[brow * 512];
            const int bswz = (brow & 7) << 4;
            __builtin_amdgcn_s_setprio(1);
            #pragma unroll
            for (int kk = 0; kk < 8; ++kk) {
                const int kb = kk * 64 + ((lane >> 4) * 16);
                bf16x8 bK = *(const bf16x8*)(kbase + (kb ^ bswz));
                s0 = __builtin_amdgcn_mfma_f32_16x16x32_bf16(qf[0][kk], bK, s0, 0, 0, 0);
                s1 = __builtin_amdgcn_mfma_f32_16x16x32_bf16(qf[1][kk], bK, s1, 0, 0, 0);
            }
            __builtin_amdgcn_s_setprio(0);
        }
        // ---- P = exp(TAU*S); row-sum partials; bf16 P to LDS ----------------
        #pragma unroll
        for (int i = 0; i < 4; ++i) {
            const float p0 = exp2f(s0[i] * TAU_LOG2E);
            const float p1 = exp2f(s1[i] * TAU_LOG2E);
            lsum[0][i] += p0;
            lsum[1][i] += p1;
            const int pr0 = wm*32 + (lane >> 4) * 4 + i;
            const int pr1 = pr0 + 16;
            const int pc2 = (wn*16 + (lane & 15)) * 2;
            *(unsigned short*)(Pls + pr0*128 + (pc2 ^ ((pr0 & 7) << 4))) = f2bf(p0);
            *(unsigned short*)(Pls + pr1*128 + (pc2 ^ ((pr1 & 7) << 4))) = f2bf(p1);
        }
        barrier_lgkm();   // P visible to all waves

        // ---- PV: O[32 x 64] += P[32 x 64] @ V[64 x 64-d-slice] --------------
        bf16x8 aP[2][2];
        #pragma unroll
        for (int mi = 0; mi < 2; ++mi)
            #pragma unroll
            for (int ks = 0; ks < 2; ++ks) {
                const int ar = wm*32 + mi*16 + (lane & 15);
                const int akb = ks*64 + ((lane >> 4) * 16);
                aP[mi][ks] = *(const bf16x8*)(Pls + ar*128 + (akb ^ ((ar & 7) << 4)));
            }
        __builtin_amdgcn_s_setprio(1);
        #pragma unroll
        for (int ks = 0; ks < 2; ++ks) {
            #pragma unroll
            for (int nf = 0; nf < 4; ++nf) {
                const int dr = wn*64 + nf*16 + (lane & 15);
                const int kb2 = ks*64 + ((lane >> 4) * 16);
                bf16x8 bV = *(const bf16x8*)(&Vtls[dr*128 + (kb2 ^ ((dr & 7) << 4))]);
                o[0][nf] = __builtin_amdgcn_mfma_f32_16x16x32_bf16(aP[0][ks], bV, o[0][nf], 0, 0, 0);
                o[1][nf] = __builtin_amdgcn_mfma_f32_16x16x32_bf16(aP[1][ks], bV, o[1][nf], 0, 0, 0);
            }
        }
        __builtin_amdgcn_s_setprio(0);
        barrier_lgkm();   // all LDS reads of this tile done -> safe to restage

        // ---- issue DMA for tile kt+1 into the (single) buffer ---------------
        if (kt + 1 < NT2) {
            const int kvn = kvbase + (kt + 1) * KB;
            #pragma unroll
            for (int it = 0; it < 4; ++it) {
                const int chunk = kchunk0 + it;
                const int krow = chunk * 2 + krow_l;
                const int kdch = kcol16 ^ (krow & 7);
                gl_lds16(Xm + (size_t)(kvn + krow) * D_DIM + kdch * 8, &Kls[chunk * 1024]);
                const int vd = chunk * 8 + vd_l;
                const int vkc = vkc16 ^ (vd & 7);
                gl_lds16(Xtm + (size_t)vd * B_ROWS + kvn + vkc * 8, &Vtls[chunk * 1024]);
            }
        }
    }

    // ---- epilogue: partial row-sums + partial O to workspace ----------------
    #pragma unroll
    for (int mi = 0; mi < 2; ++mi)
        #pragma unroll
        for (int i = 0; i < 4; ++i) {
            float v = lsum[mi][i];
            v += __shfl_xor(v, 1); v += __shfl_xor(v, 2);
            v += __shfl_xor(v, 4); v += __shfl_xor(v, 8);
            if ((lane & 15) == 0)
                lsum_sh[wn][wm*32 + mi*16 + (lane >> 4)*4 + i] = v;
        }
    __syncthreads();
    if (tid < QB)
        lsum_part[(size_t)blockIdx.x * QB + tid] =
            lsum_sh[0][tid] + lsum_sh[1][tid] + lsum_sh[2][tid] + lsum_sh[3][tid];

    float* Ob = Opart + (size_t)blockIdx.x * QB * D_DIM;
    #pragma unroll
    for (int mi = 0; mi < 2; ++mi)
        #pragma unroll
        for (int nf = 0; nf < 4; ++nf)
            #pragma unroll
            for (int i = 0; i < 4; ++i) {
                const int row = wm*32 + mi*16 + (lane >> 4)*4 + i;
                const int col = wn*64 + nf*16 + (lane & 15);
                Ob[row * D_DIM + col] = o[mi][nf][i];
            }
}

// ---- combine halves + spec-smooth epilogue + loss, fused --------------------
// grid = 2048 blocks x 256 thr (4 waves); wave handles one row r.
__global__ __launch_bounds__(256) void k_combine_loss(
    const float* __restrict__ Xf, const float* __restrict__ Opart,
    const float* __restrict__ lsum_part, float* __restrict__ out)
{
    __shared__ float part[4];
    const int w = threadIdx.x >> 6;
    const int lane = threadIdx.x & 63;
    const int r = blockIdx.x * 4 + w;
    const int qb = r >> 6, ri = r & 63;

    float y[2][4];
    float nrm[2];
    #pragma unroll
    for (int m = 0; m < 2; ++m) {
        const int blk0 = m * 256 + qb * 2;
        const float l = lsum_part[(size_t)blk0 * QB + ri]
                      + lsum_part[(size_t)(blk0 + 1) * QB + ri];
        const float c = ALPHA / l;
        const float4 x  = *(const float4*)(Xf + ((size_t)m * B_ROWS + r) * D_DIM + lane * 4);
        const float4 o0 = *(const float4*)(Opart + ((size_t)blk0 * QB + ri) * D_DIM + lane * 4);
        const float4 o1 = *(const float4*)(Opart + ((size_t)(blk0 + 1) * QB + ri) * D_DIM + lane * 4);
        y[m][0] = x.x - c * (o0.x + o1.x);
        y[m][1] = x.y - c * (o0.y + o1.y);
        y[m][2] = x.z - c * (o0.z + o1.z);
        y[m][3] = x.w - c * (o0.w + o1.w);
        float s = y[m][0]*y[m][0] + y[m][1]*y[m][1] + y[m][2]*y[m][2] + y[m][3]*y[m][3];
        #pragma unroll
        for (int mask = 32; mask; mask >>= 1) s += __shfl_xor(s, mask);
        nrm[m] = s;
    }
    float d = y[0][0]*y[1][0] + y[0][1]*y[1][1] + y[0][2]*y[1][2] + y[0][3]*y[1][3];
    #pragma unroll
    for (int mask = 32; mask; mask >>= 1) d += __shfl_xor(d, mask);
    if (lane == 0) {
        // yhat = y * ||y|| (SHRINK_NORM=1) => dot = ||yu||*||yp||*sum(yu.yp)
        const float z = sqrtf(nrm[0] * nrm[1]) * d;
        part[w] = log1pf(expf(-z));
    }
    __syncthreads();
    if (threadIdx.x == 0)
        atomicAdd(out, (part[0] + part[1] + part[2] + part[3]) * (1.0f / 8192.0f));
}

// ============ FALLBACK PATH (exact round-4 kernels, ws <= 32MB) ==============
__global__ __launch_bounds__(512, 2) void k_flash(
    const unsigned short* __restrict__ Xh, const unsigned short* __restrict__ Xht,
    float* __restrict__ Xf)
{
    __shared__ unsigned char Kls[2][64 * 512];
    __shared__ unsigned char Vtls[2][256 * 128];
    __shared__ unsigned char Pls[64 * 128];
    __shared__ float lsum_sh[4][QB];
    __shared__ float nrm_sh[4][QB];

    const int tid = threadIdx.x;
    const int lane = tid & 63;
    const int w = tid >> 6;
    const int wm = w >> 2;
    const int wn = w & 3;
    const int m = blockIdx.x >> 7;
    const int q0 = (blockIdx.x & 127) * QB;

    const unsigned short* Xm  = Xh  + (size_t)m * B_ROWS * D_DIM;
    const unsigned short* Xtm = Xht + (size_t)m * D_DIM * B_ROWS;
    float* Xfm = Xf + (size_t)m * B_ROWS * D_DIM;

    bf16x8 qf[2][8];
    #pragma unroll
    for (int mi = 0; mi < 2; ++mi) {
        const unsigned short* qbp = Xm + (size_t)(q0 + wm*32 + mi*16 + (lane & 15)) * D_DIM
                                       + (lane >> 4) * 8;
        #pragma unroll
        for (int kk = 0; kk < 8; ++kk)
            qf[mi][kk] = *(const bf16x8*)(qbp + kk * 32);
    }

    const int kchunk0 = w * 4;
    const int krow_l  = (lane >> 5);
    const int kcol16  = lane & 31;
    const int vd_l    = (lane >> 3);
    const int vkc16   = lane & 7;

    #pragma unroll
    for (int it = 0; it < 4; ++it) {
        const int chunk = kchunk0 + it;
        const int krow = chunk * 2 + krow_l;
        const int kdch = kcol16 ^ (krow & 7);
        gl_lds16(Xm + (size_t)krow * D_DIM + kdch * 8, &Kls[0][chunk * 1024]);
        const int vd = chunk * 8 + vd_l;
        const int vkc = vkc16 ^ (vd & 7);
        gl_lds16(Xtm + (size_t)vd * B_ROWS + vkc * 8, &Vtls[0][chunk * 1024]);
    }
    barrier_all();

    f32x4 o[2][4];
    #pragma unroll
    for (int mi = 0; mi < 2; ++mi)
        #pragma unroll
        for (int nf = 0; nf < 4; ++nf) o[mi][nf] = (f32x4){0.f, 0.f, 0.f, 0.f};
    float lsum[2][4] = {{0.f,0.f,0.f,0.f},{0.f,0.f,0.f,0.f}};
    int cur = 0;

    for (int kt = 0; kt < NT; ++kt) {
        const int nxt = cur ^ 1;
        if (kt + 1 < NT) {
            const int kvn = (kt + 1) * KB;
            #pragma unroll
            for (int it = 0; it < 4; ++it) {
                const int chunk = kchunk0 + it;
                const int krow = chunk * 2 + krow_l;
                const int kdch = kcol16 ^ (krow & 7);
                gl_lds16(Xm + (size_t)(kvn + krow) * D_DIM + kdch * 8, &Kls[nxt][chunk * 1024]);
                const int vd = chunk * 8 + vd_l;
                const int vkc = vkc16 ^ (vd & 7);
                gl_lds16(Xtm + (size_t)vd * B_ROWS + kvn + vkc * 8, &Vtls[nxt][chunk * 1024]);
            }
        }
        f32x4 s0 = {0.f,0.f,0.f,0.f}, s1 = {0.f,0.f,0.f,0.f};
        {
            const int brow = wn * 16 + (lane & 15);
            const unsigned char* kbase = &Kls[cur][brow * 512];
            const int bswz = (brow & 7) << 4;
            #pragma unroll
            for (int kk = 0; kk < 8; ++kk) {
                const int kb = kk * 64 + ((lane >> 4) * 16);
                bf16x8 bK = *(const bf16x8*)(kbase + (kb ^ bswz));
                s0 = __builtin_amdgcn_mfma_f32_16x16x32_bf16(qf[0][kk], bK, s0, 0, 0, 0);
                s1 = __builtin_amdgcn_mfma_f32_16x16x32_bf16(qf[1][kk], bK, s1, 0, 0, 0);
            }
        }
        #pragma unroll
        for (int i = 0; i < 4; ++i) {
            const float p0 = exp2f(s0[i] * TAU_LOG2E);
            const float p1 = exp2f(s1[i] * TAU_LOG2E);
            lsum[0][i] += p0;
            lsum[1][i] += p1;
            const int pr0 = wm*32 + (lane >> 4) * 4 + i;
            const int pr1 = pr0 + 16;
            const int pc2 = (wn*16 + (lane & 15)) * 2;
            *(unsigned short*)(Pls + pr0*128 + (pc2 ^ ((pr0 & 7) << 4))) = f2bf(p0);
            *(unsigned short*)(Pls + pr1*128 + (pc2 ^ ((pr1 & 7) << 4))) = f2bf(p1);
        }
        barrier_lgkm();
        bf16x8 aP[2][2];
        #pragma unroll
        for (int mi = 0; mi < 2; ++mi)
            #pragma unroll
            for (int ks = 0; ks < 2; ++ks) {
                const int ar = wm*32 + mi*16 + (lane & 15);
                const int akb = ks*64 + ((lane >> 4) * 16);
                aP[mi][ks] = *(const bf16x8*)(Pls + ar*128 + (akb ^ ((ar & 7) << 4)));
            }
        #pragma unroll
        for (int ks = 0; ks < 2; ++ks) {
            #pragma unroll
            for (int nf = 0; nf < 4; ++nf) {
                const int dr = wn*64 + nf*16 + (lane & 15);
                const int kb2 = ks*64 + ((lane >> 4) * 16);
                bf16x8 bV = *(const bf16x8*)(&Vtls[cur][dr*128 + (kb2 ^ ((dr & 7) << 4))]);
                o[0][nf] = __builtin_amdgcn_mfma_f32_16x16x32_bf16(aP[0][ks], bV, o[0][nf], 0, 0, 0);
                o[1][nf] = __builtin_amdgcn_mfma_f32_16x16x32_bf16(aP[1][ks], bV, o[1][nf], 0, 0, 0);
            }
        }
        barrier_all();
        cur = nxt;
    }

    #pragma unroll
    for (int mi = 0; mi < 2; ++mi)
        #pragma unroll
        for (int i = 0; i < 4; ++i) {
            float v = lsum[mi][i];
            v += __shfl_xor(v, 1); v += __shfl_xor(v, 2);
            v += __shfl_xor(v, 4); v += __shfl_xor(v, 8);
            if ((lane & 15) == 0)
                lsum_sh[wn][wm*32 + mi*16 + (lane >> 4)*4 + i] = v;
        }
    __syncthreads();

    float nrm[2][4] = {{0.f,0.f,0.f,0.f},{0.f,0.f,0.f,0.f}};
    #pragma unroll
    for (int mi = 0; mi < 2; ++mi)
        #pragma unroll
        for (int nf = 0; nf < 4; ++nf)
            #pragma unroll
            for (int i = 0; i < 4; ++i) {
                const int row = wm*32 + mi*16 + (lane >> 4)*4 + i;
                const int col = wn*64 + nf*16 + (lane & 15);
                const float x = Xfm[(size_t)(q0 + row) * D_DIM + col];
                const float lt = lsum_sh[0][row] + lsum_sh[1][row]
                               + lsum_sh[2][row] + lsum_sh[3][row];
                const float yv = x - (ALPHA / lt) * o[mi][nf][i];
                o[mi][nf][i] = yv;
                nrm[mi][i] += yv * yv;
            }
    #pragma unroll
    for (int mi = 0; mi < 2; ++mi)
        #pragma unroll
        for (int i = 0; i < 4; ++i) {
            float v = nrm[mi][i];
            v += __shfl_xor(v, 1); v += __shfl_xor(v, 2);
            v += __shfl_xor(v, 4); v += __shfl_xor(v, 8);
            if ((lane & 15) == 0)
                nrm_sh[wn][wm*32 + mi*16 + (lane >> 4)*4 + i] = v;
        }
    __syncthreads();
    #pragma unroll
    for (int mi = 0; mi < 2; ++mi)
        #pragma unroll
        for (int nf = 0; nf < 4; ++nf)
            #pragma unroll
            for (int i = 0; i < 4; ++i) {
                const int row = wm*32 + mi*16 + (lane >> 4)*4 + i;
                const int col = wn*64 + nf*16 + (lane & 15);
                const float scale = sqrtf(nrm_sh[0][row] + nrm_sh[1][row]
                                        + nrm_sh[2][row] + nrm_sh[3][row]);
                Xfm[(size_t)(q0 + row) * D_DIM + col] = o[mi][nf][i] * scale;
            }
}

__global__ __launch_bounds__(256) void k_loss(
    const float* __restrict__ Yu, const float* __restrict__ Yp,
    float* __restrict__ out)
{
    __shared__ float part[4];
    const int w = threadIdx.x >> 6;
    const int lane = threadIdx.x & 63;
    float acc = 0.0f;
    #pragma unroll
    for (int r = 0; r < 8; ++r) {
        const int row = blockIdx.x * 32 + w * 8 + r;
        const float4 a = *(const float4*)(Yu + (size_t)row * D_DIM + lane * 4);
        const float4 b = *(const float4*)(Yp + (size_t)row * D_DIM + lane * 4);
        float dot = a.x*b.x + a.y*b.y + a.z*b.z + a.w*b.w;
        #pragma unroll
        for (int mask = 32; mask; mask >>= 1) dot += __shfl_xor(dot, mask);
        if (lane == 0) acc += log1pf(expf(-dot));
    }
    if (lane == 0) part[w] = acc;
    __syncthreads();
    if (threadIdx.x == 0) {
        const float s = part[0] + part[1] + part[2] + part[3];
        atomicAdd(out, s * (1.0f / 8192.0f));
    }
}

extern "C" void kernel_launch(void* const* d_in, const int* in_sizes, int n_in,
                              void* d_out, int out_size, void* d_ws, size_t ws_size,
                              hipStream_t stream) {
    const float* ue = (const float*)d_in[0];
    const float* ie = (const float*)d_in[1];
    const int*   u  = (const int*)d_in[2];
    const int*   p  = (const int*)d_in[3];
    float* out = (float*)d_out;

    char* ws = (char*)d_ws;
    float* Xf            = (float*)ws;                              // 16 MB
    unsigned short* Xh   = (unsigned short*)(ws + (16u << 20));     //  8 MB
    unsigned short* Xht  = (unsigned short*)(ws + (24u << 20));     //  8 MB
    float* Opart         = (float*)(ws + (32u << 20));              // 32 MB
    float* lsum_part     = (float*)(ws + (64u << 20));              // 128 KB

    const size_t need = (64u << 20) + (128u << 10);

    k_gather_norm<<<4096, 256, 0, stream>>>(ue, ie, u, p, Xf, Xh, out);
    k_transpose <<<1024, 256, 0, stream>>>(Xh, Xht);
    if (ws_size >= need) {
        k_flash_part  <<<512, 512, 0, stream>>>(Xh, Xht, Opart, lsum_part);
        k_combine_loss<<<2048, 256, 0, stream>>>(Xf, Opart, lsum_part, out);
    } else {
        k_flash<<<256, 512, 0, stream>>>(Xh, Xht, Xf);
        k_loss <<<256, 256, 0, stream>>>(Xf, Xf + (size_t)B_ROWS * D_DIM, out);
    }
}

// Round 7
// 419.807 us; speedup vs baseline: 1.0818x; 1.0818x over previous
//
#include <hip/hip_runtime.h>
#include <hip/hip_bf16.h>

#define B_ROWS 8192
#define D_DIM  256
#define QB     64
#define KB     64
#define NT     (B_ROWS / KB)
#define ALPHA  0.8f
// TAU * log2(e) = 3.0 * 1.4426950408889634
#define TAU_LOG2E 4.328085122666890f

typedef __attribute__((ext_vector_type(8))) short bf16x8;
typedef __attribute__((ext_vector_type(4))) float f32x4;
typedef __attribute__((ext_vector_type(4))) unsigned short ushort4v;

__device__ inline unsigned short f2bf(float f) {
    unsigned int u = __builtin_bit_cast(unsigned int, f);
    u += 0x7FFF + ((u >> 16) & 1);   // RNE (finite values)
    return (unsigned short)(u >> 16);
}

// global -> LDS DMA, 16B per lane. LDS dest = wave-uniform base + lane*16
// (linear); the swizzle is applied to the per-lane GLOBAL source instead.
__device__ inline void gl_lds16(const void* g, void* l) {
    __builtin_amdgcn_global_load_lds(
        (const __attribute__((address_space(1))) unsigned int*)g,
        (__attribute__((address_space(3))) unsigned int*)l, 16, 0, 0);
}

__device__ inline void bar() {
    asm volatile("" ::: "memory");
    __builtin_amdgcn_s_barrier();
    asm volatile("" ::: "memory");
}
__device__ inline void wait_lgkm() {
    asm volatile("s_waitcnt lgkmcnt(0)" ::: "memory");
}
__device__ inline void wait_vm() {
    asm volatile("s_waitcnt vmcnt(0)" ::: "memory");
}

// ---------------- Kernel A: gather + row-normalize, emit f32 + bf16 copies --
__global__ __launch_bounds__(256) void k_gather_norm(
    const float* __restrict__ ue, const float* __restrict__ ie,
    const int* __restrict__ u, const int* __restrict__ p,
    float* __restrict__ Xf, unsigned short* __restrict__ Xh,
    float* __restrict__ out)
{
    const int b = blockIdx.x * 4 + (threadIdx.x >> 6);   // 0..16383
    const int lane = threadIdx.x & 63;
    if (b == 0 && lane == 0) out[0] = 0.0f;   // init accumulator (d_out is poisoned)
    const int m = b >> 13;
    const int r = b & 8191;
    const float* src = (m == 0) ? (ue + (size_t)u[r] * D_DIM)
                                : (ie + (size_t)p[r] * D_DIM);
    float4 v = ((const float4*)src)[lane];
    float ss = v.x*v.x + v.y*v.y + v.z*v.z + v.w*v.w;
    #pragma unroll
    for (int mask = 32; mask; mask >>= 1) ss += __shfl_xor(ss, mask);
    const float inv = 1.0f / sqrtf(ss);
    v.x *= inv; v.y *= inv; v.z *= inv; v.w *= inv;
    const size_t off = (size_t)(m * B_ROWS + r) * D_DIM + lane * 4;
    *(float4*)(Xf + off) = v;
    ushort4v h = { f2bf(v.x), f2bf(v.y), f2bf(v.z), f2bf(v.w) };
    *(ushort4v*)(Xh + off) = h;
}

// ---------------- Kernel T: bf16 transpose [2][8192][256] -> [2][256][8192] --
__global__ __launch_bounds__(256) void k_transpose(
    const unsigned short* __restrict__ Xh, unsigned short* __restrict__ Xht)
{
    __shared__ unsigned short tile[64 * 84];
    const int bid = blockIdx.x;                // 0..1023
    const int m = bid >> 9;
    const int t = bid & 511;
    const int rt = t >> 2, ct = t & 3;
    const int r0 = rt * 64, c0 = ct * 64;
    const int tid = threadIdx.x;
    const unsigned short* src = Xh + (size_t)m * B_ROWS * D_DIM;
    unsigned short* dst = Xht + (size_t)m * D_DIM * B_ROWS;
    #pragma unroll
    for (int ph = 0; ph < 2; ++ph) {
        const int row = ph * 32 + (tid >> 3);
        const int ch = tid & 7;
        const unsigned short* s = src + (size_t)(r0 + row) * D_DIM + c0 + ch * 8;
        ushort4v a = *(const ushort4v*)s;
        ushort4v b = *(const ushort4v*)(s + 4);
        *(ushort4v*)(&tile[row * 84 + ch * 8]) = a;
        *(ushort4v*)(&tile[row * 84 + ch * 8 + 4]) = b;
    }
    __syncthreads();
    #pragma unroll
    for (int ph = 0; ph < 2; ++ph) {
        const int d = ph * 32 + (tid >> 3);
        const int kc = tid & 7;
        ushort4v lo = { tile[(kc*8+0)*84 + d], tile[(kc*8+1)*84 + d],
                        tile[(kc*8+2)*84 + d], tile[(kc*8+3)*84 + d] };
        ushort4v hi = { tile[(kc*8+4)*84 + d], tile[(kc*8+5)*84 + d],
                        tile[(kc*8+6)*84 + d], tile[(kc*8+7)*84 + d] };
        unsigned short* o = dst + (size_t)(c0 + d) * B_ROWS + r0 + kc * 8;
        *(ushort4v*)o = lo;
        *(ushort4v*)(o + 4) = hi;
    }
}

// ---------------- Kernel B: flash spec-smooth v4 (m201-style phase schedule) -
// grid = 256 blocks (2 matrices x 128 Q-blocks), 512 threads (8 waves, 2Mx4N).
// Double-buffered K/V via global_load_lds (pre-swizzled global src).
// Per KV-iter, 4 phases, each {ds_read subtile (+DMA issue) -> barrier ->
// lgkmcnt(0) -> setprio MFMA x8 setprio -> barrier}; one vmcnt(0)/iter.
__global__ __launch_bounds__(512, 2) void k_flash(
    const unsigned short* __restrict__ Xh,   // [2][8192][256] bf16
    const unsigned short* __restrict__ Xht,  // [2][256][8192] bf16
    float* __restrict__ Xf)                  // [2][8192][256] f32; overwritten with Y
{
    __shared__ unsigned char Kls[2][64 * 512];    // 2 x 32KB, 16B-XOR-swizzled rows
    __shared__ unsigned char Vtls[2][256 * 128];  // 2 x 32KB: d-major, 64 kv per row
    __shared__ unsigned char Pls[64 * 128];       // 8KB: 64 q-rows x 64 kv bf16
    __shared__ float lsum_sh[4][QB];
    __shared__ float nrm_sh[4][QB];

    const int tid = threadIdx.x;
    const int lane = tid & 63;
    const int w = tid >> 6;
    const int wm = w >> 2;            // 0..1: q-row group (32 rows)
    const int wn = w & 3;             // 0..3: QK col-group / PV d-group
    const int m = blockIdx.x >> 7;
    const int q0 = (blockIdx.x & 127) * QB;

    const unsigned short* Xm  = Xh  + (size_t)m * B_ROWS * D_DIM;
    const unsigned short* Xtm = Xht + (size_t)m * D_DIM * B_ROWS;
    float* Xfm = Xf + (size_t)m * B_ROWS * D_DIM;

    // ---- Q fragments in registers: rows wm*32+mi*16+(lane&15) ---------------
    bf16x8 qf[2][8];
    #pragma unroll
    for (int mi = 0; mi < 2; ++mi) {
        const unsigned short* qbp = Xm + (size_t)(q0 + wm*32 + mi*16 + (lane & 15)) * D_DIM
                                       + (lane >> 4) * 8;
        #pragma unroll
        for (int kk = 0; kk < 8; ++kk)
            qf[mi][kk] = *(const bf16x8*)(qbp + kk * 32);
    }

    // ---- DMA staging geometry ------------------------------------------------
    const int kchunk0 = w * 4;
    const int krow_l  = (lane >> 5);
    const int kcol16  = lane & 31;
    const int vd_l    = (lane >> 3);
    const int vkc16   = lane & 7;

    // ---- LDS read address bases (loop-invariant) ----------------------------
    const int brow  = wn * 16 + (lane & 15);          // K row for QK B-frag
    const int bswz  = (brow & 7) << 4;
    const int kqoff = (lane >> 4) * 16;               // k-slot offset within 64B
    const int ar0   = wm*32 + (lane & 15);            // P row, mi=0
    const int ar1   = ar0 + 16;                       // P row, mi=1

    // ---- prologue: stage tile 0 into buffer 0 -------------------------------
    #pragma unroll
    for (int it = 0; it < 4; ++it) {
        const int chunk = kchunk0 + it;
        const int krow = chunk * 2 + krow_l;
        const int kdch = kcol16 ^ (krow & 7);
        gl_lds16(Xm + (size_t)krow * D_DIM + kdch * 8, &Kls[0][chunk * 1024]);
        const int vd = chunk * 8 + vd_l;
        const int vkc = vkc16 ^ (vd & 7);
        gl_lds16(Xtm + (size_t)vd * B_ROWS + vkc * 8, &Vtls[0][chunk * 1024]);
    }
    wait_vm();
    bar();

    f32x4 o[2][4];
    #pragma unroll
    for (int mi = 0; mi < 2; ++mi)
        #pragma unroll
        for (int nf = 0; nf < 4; ++nf) o[mi][nf] = (f32x4){0.f, 0.f, 0.f, 0.f};
    float lsum[2][4] = {{0.f,0.f,0.f,0.f},{0.f,0.f,0.f,0.f}};
    int cur = 0;

    for (int kt = 0; kt < NT; ++kt) {
        const int nxt = cur ^ 1;
        const bool pf = (kt + 1 < NT);
        const int kvn = (kt + 1) * KB;
        const unsigned char* Kb = &Kls[cur][brow * 512];
        const unsigned char* Vb = &Vtls[cur][0];

        // ================= Phase A: QK kk 0..3 ===============================
        if (pf) {   // 4 K-DMAs -> Kls[nxt]
            #pragma unroll
            for (int it = 0; it < 4; ++it) {
                const int chunk = kchunk0 + it;
                const int krow = chunk * 2 + krow_l;
                const int kdch = kcol16 ^ (krow & 7);
                gl_lds16(Xm + (size_t)(kvn + krow) * D_DIM + kdch * 8,
                         &Kls[nxt][chunk * 1024]);
            }
        }
        bf16x8 bk0 = *(const bf16x8*)(Kb + ((0*64 + kqoff) ^ bswz));
        bf16x8 bk1 = *(const bf16x8*)(Kb + ((1*64 + kqoff) ^ bswz));
        bf16x8 bk2 = *(const bf16x8*)(Kb + ((2*64 + kqoff) ^ bswz));
        bf16x8 bk3 = *(const bf16x8*)(Kb + ((3*64 + kqoff) ^ bswz));
        bar();
        wait_lgkm();
        f32x4 s0 = {0.f,0.f,0.f,0.f}, s1 = {0.f,0.f,0.f,0.f};
        __builtin_amdgcn_s_setprio(1);
        s0 = __builtin_amdgcn_mfma_f32_16x16x32_bf16(qf[0][0], bk0, s0, 0, 0, 0);
        s1 = __builtin_amdgcn_mfma_f32_16x16x32_bf16(qf[1][0], bk0, s1, 0, 0, 0);
        s0 = __builtin_amdgcn_mfma_f32_16x16x32_bf16(qf[0][1], bk1, s0, 0, 0, 0);
        s1 = __builtin_amdgcn_mfma_f32_16x16x32_bf16(qf[1][1], bk1, s1, 0, 0, 0);
        s0 = __builtin_amdgcn_mfma_f32_16x16x32_bf16(qf[0][2], bk2, s0, 0, 0, 0);
        s1 = __builtin_amdgcn_mfma_f32_16x16x32_bf16(qf[1][2], bk2, s1, 0, 0, 0);
        s0 = __builtin_amdgcn_mfma_f32_16x16x32_bf16(qf[0][3], bk3, s0, 0, 0, 0);
        s1 = __builtin_amdgcn_mfma_f32_16x16x32_bf16(qf[1][3], bk3, s1, 0, 0, 0);
        __builtin_amdgcn_s_setprio(0);
        bar();

        // ================= Phase B: QK kk 4..7 ===============================
        if (pf) {   // 4 V-DMAs -> Vtls[nxt]
            #pragma unroll
            for (int it = 0; it < 4; ++it) {
                const int chunk = kchunk0 + it;
                const int vd = chunk * 8 + vd_l;
                const int vkc = vkc16 ^ (vd & 7);
                gl_lds16(Xtm + (size_t)vd * B_ROWS + kvn + vkc * 8,
                         &Vtls[nxt][chunk * 1024]);
            }
        }
        bf16x8 bk4 = *(const bf16x8*)(Kb + ((4*64 + kqoff) ^ bswz));
        bf16x8 bk5 = *(const bf16x8*)(Kb + ((5*64 + kqoff) ^ bswz));
        bf16x8 bk6 = *(const bf16x8*)(Kb + ((6*64 + kqoff) ^ bswz));
        bf16x8 bk7 = *(const bf16x8*)(Kb + ((7*64 + kqoff) ^ bswz));
        bar();
        wait_lgkm();
        __builtin_amdgcn_s_setprio(1);
        s0 = __builtin_amdgcn_mfma_f32_16x16x32_bf16(qf[0][4], bk4, s0, 0, 0, 0);
        s1 = __builtin_amdgcn_mfma_f32_16x16x32_bf16(qf[1][4], bk4, s1, 0, 0, 0);
        s0 = __builtin_amdgcn_mfma_f32_16x16x32_bf16(qf[0][5], bk5, s0, 0, 0, 0);
        s1 = __builtin_amdgcn_mfma_f32_16x16x32_bf16(qf[1][5], bk5, s1, 0, 0, 0);
        s0 = __builtin_amdgcn_mfma_f32_16x16x32_bf16(qf[0][6], bk6, s0, 0, 0, 0);
        s1 = __builtin_amdgcn_mfma_f32_16x16x32_bf16(qf[1][6], bk6, s1, 0, 0, 0);
        s0 = __builtin_amdgcn_mfma_f32_16x16x32_bf16(qf[0][7], bk7, s0, 0, 0, 0);
        s1 = __builtin_amdgcn_mfma_f32_16x16x32_bf16(qf[1][7], bk7, s1, 0, 0, 0);
        __builtin_amdgcn_s_setprio(0);
        bar();

        // ================= Phase C: exp/P-write + PV ks=0 ====================
        #pragma unroll
        for (int i = 0; i < 4; ++i) {
            const float p0 = exp2f(s0[i] * TAU_LOG2E);
            const float p1 = exp2f(s1[i] * TAU_LOG2E);
            lsum[0][i] += p0;
            lsum[1][i] += p1;
            const int pr0 = wm*32 + (lane >> 4) * 4 + i;
            const int pr1 = pr0 + 16;
            const int pc2 = (wn*16 + (lane & 15)) * 2;
            *(unsigned short*)(Pls + pr0*128 + (pc2 ^ ((pr0 & 7) << 4))) = f2bf(p0);
            *(unsigned short*)(Pls + pr1*128 + (pc2 ^ ((pr1 & 7) << 4))) = f2bf(p1);
        }
        bf16x8 v0, v1, v2, v3;
        {
            const int dr0 = wn*64 + 0*16 + (lane & 15);
            const int dr1 = wn*64 + 1*16 + (lane & 15);
            const int dr2 = wn*64 + 2*16 + (lane & 15);
            const int dr3 = wn*64 + 3*16 + (lane & 15);
            v0 = *(const bf16x8*)(Vb + dr0*128 + ((0*64 + kqoff) ^ ((dr0 & 7) << 4)));
            v1 = *(const bf16x8*)(Vb + dr1*128 + ((0*64 + kqoff) ^ ((dr1 & 7) << 4)));
            v2 = *(const bf16x8*)(Vb + dr2*128 + ((0*64 + kqoff) ^ ((dr2 & 7) << 4)));
            v3 = *(const bf16x8*)(Vb + dr3*128 + ((0*64 + kqoff) ^ ((dr3 & 7) << 4)));
        }
        wait_lgkm();    // flush own P-writes before the barrier
        bar();          // P tile complete & visible
        bf16x8 a00 = *(const bf16x8*)(Pls + ar0*128 + ((0*64 + kqoff) ^ ((ar0 & 7) << 4)));
        bf16x8 a10 = *(const bf16x8*)(Pls + ar1*128 + ((0*64 + kqoff) ^ ((ar1 & 7) << 4)));
        wait_lgkm();
        __builtin_amdgcn_s_setprio(1);
        o[0][0] = __builtin_amdgcn_mfma_f32_16x16x32_bf16(a00, v0, o[0][0], 0, 0, 0);
        o[1][0] = __builtin_amdgcn_mfma_f32_16x16x32_bf16(a10, v0, o[1][0], 0, 0, 0);
        o[0][1] = __builtin_amdgcn_mfma_f32_16x16x32_bf16(a00, v1, o[0][1], 0, 0, 0);
        o[1][1] = __builtin_amdgcn_mfma_f32_16x16x32_bf16(a10, v1, o[1][1], 0, 0, 0);
        o[0][2] = __builtin_amdgcn_mfma_f32_16x16x32_bf16(a00, v2, o[0][2], 0, 0, 0);
        o[1][2] = __builtin_amdgcn_mfma_f32_16x16x32_bf16(a10, v2, o[1][2], 0, 0, 0);
        o[0][3] = __builtin_amdgcn_mfma_f32_16x16x32_bf16(a00, v3, o[0][3], 0, 0, 0);
        o[1][3] = __builtin_amdgcn_mfma_f32_16x16x32_bf16(a10, v3, o[1][3], 0, 0, 0);
        __builtin_amdgcn_s_setprio(0);
        bar();

        // ================= Phase D: PV ks=1 + drain ==========================
        bf16x8 a01 = *(const bf16x8*)(Pls + ar0*128 + ((1*64 + kqoff) ^ ((ar0 & 7) << 4)));
        bf16x8 a11 = *(const bf16x8*)(Pls + ar1*128 + ((1*64 + kqoff) ^ ((ar1 & 7) << 4)));
        bf16x8 v4, v5, v6, v7;
        {
            const int dr0 = wn*64 + 0*16 + (lane & 15);
            const int dr1 = wn*64 + 1*16 + (lane & 15);
            const int dr2 = wn*64 + 2*16 + (lane & 15);
            const int dr3 = wn*64 + 3*16 + (lane & 15);
            v4 = *(const bf16x8*)(Vb + dr0*128 + ((1*64 + kqoff) ^ ((dr0 & 7) << 4)));
            v5 = *(const bf16x8*)(Vb + dr1*128 + ((1*64 + kqoff) ^ ((dr1 & 7) << 4)));
            v6 = *(const bf16x8*)(Vb + dr2*128 + ((1*64 + kqoff) ^ ((dr2 & 7) << 4)));
            v7 = *(const bf16x8*)(Vb + dr3*128 + ((1*64 + kqoff) ^ ((dr3 & 7) << 4)));
        }
        wait_lgkm();
        __builtin_amdgcn_s_setprio(1);
        o[0][0] = __builtin_amdgcn_mfma_f32_16x16x32_bf16(a01, v4, o[0][0], 0, 0, 0);
        o[1][0] = __builtin_amdgcn_mfma_f32_16x16x32_bf16(a11, v4, o[1][0], 0, 0, 0);
        o[0][1] = __builtin_amdgcn_mfma_f32_16x16x32_bf16(a01, v5, o[0][1], 0, 0, 0);
        o[1][1] = __builtin_amdgcn_mfma_f32_16x16x32_bf16(a11, v5, o[1][1], 0, 0, 0);
        o[0][2] = __builtin_amdgcn_mfma_f32_16x16x32_bf16(a01, v6, o[0][2], 0, 0, 0);
        o[1][2] = __builtin_amdgcn_mfma_f32_16x16x32_bf16(a11, v6, o[1][2], 0, 0, 0);
        o[0][3] = __builtin_amdgcn_mfma_f32_16x16x32_bf16(a01, v7, o[0][3], 0, 0, 0);
        o[1][3] = __builtin_amdgcn_mfma_f32_16x16x32_bf16(a11, v7, o[1][3], 0, 0, 0);
        __builtin_amdgcn_s_setprio(0);
        wait_vm();      // drain this iter's 8 prefetch DMAs (cover = phases B..D)
        bar();          // iter boundary: nxt fully staged, Pls/cur reads done
        cur = nxt;
    }

    // ---- epilogue -----------------------------------------------------------
    #pragma unroll
    for (int mi = 0; mi < 2; ++mi)
        #pragma unroll
        for (int i = 0; i < 4; ++i) {
            float v = lsum[mi][i];
            v += __shfl_xor(v, 1); v += __shfl_xor(v, 2);
            v += __shfl_xor(v, 4); v += __shfl_xor(v, 8);
            if ((lane & 15) == 0)
                lsum_sh[wn][wm*32 + mi*16 + (lane >> 4)*4 + i] = v;
        }
    __syncthreads();

    float nrm[2][4] = {{0.f,0.f,0.f,0.f},{0.f,0.f,0.f,0.f}};
    #pragma unroll
    for (int mi = 0; mi < 2; ++mi)
        #pragma unroll
        for (int nf = 0; nf < 4; ++nf)
            #pragma unroll
            for (int i = 0; i < 4; ++i) {
                const int row = wm*32 + mi*16 + (lane >> 4)*4 + i;
                const int col = wn*64 + nf*16 + (lane & 15);
                const float x = Xfm[(size_t)(q0 + row) * D_DIM + col];
                const float lt = lsum_sh[0][row] + lsum_sh[1][row]
                               + lsum_sh[2][row] + lsum_sh[3][row];
                const float yv = x - (ALPHA / lt) * o[mi][nf][i];
                o[mi][nf][i] = yv;
                nrm[mi][i] += yv * yv;
            }
    #pragma unroll
    for (int mi = 0; mi < 2; ++mi)
        #pragma unroll
        for (int i = 0; i < 4; ++i) {
            float v = nrm[mi][i];
            v += __shfl_xor(v, 1); v += __shfl_xor(v, 2);
            v += __shfl_xor(v, 4); v += __shfl_xor(v, 8);
            if ((lane & 15) == 0)
                nrm_sh[wn][wm*32 + mi*16 + (lane >> 4)*4 + i] = v;
        }
    __syncthreads();
    #pragma unroll
    for (int mi = 0; mi < 2; ++mi)
        #pragma unroll
        for (int nf = 0; nf < 4; ++nf)
            #pragma unroll
            for (int i = 0; i < 4; ++i) {
                const int row = wm*32 + mi*16 + (lane >> 4)*4 + i;
                const int col = wn*64 + nf*16 + (lane & 15);
                const float scale = sqrtf(nrm_sh[0][row] + nrm_sh[1][row]
                                        + nrm_sh[2][row] + nrm_sh[3][row]);
                Xfm[(size_t)(q0 + row) * D_DIM + col] = o[mi][nf][i] * scale;
            }
}

// ---------------- Kernel C: loss = mean(log1p(exp(-dot(fu,fp)))) -------------
__global__ __launch_bounds__(256) void k_loss(
    const float* __restrict__ Yu, const float* __restrict__ Yp,
    float* __restrict__ out)
{
    __shared__ float part[4];
    const int w = threadIdx.x >> 6;
    const int lane = threadIdx.x & 63;
    float acc = 0.0f;
    #pragma unroll
    for (int r = 0; r < 8; ++r) {
        const int row = blockIdx.x * 32 + w * 8 + r;
        const float4 a = *(const float4*)(Yu + (size_t)row * D_DIM + lane * 4);
        const float4 b = *(const float4*)(Yp + (size_t)row * D_DIM + lane * 4);
        float dot = a.x*b.x + a.y*b.y + a.z*b.z + a.w*b.w;
        #pragma unroll
        for (int mask = 32; mask; mask >>= 1) dot += __shfl_xor(dot, mask);
        if (lane == 0) acc += log1pf(expf(-dot));
    }
    if (lane == 0) part[w] = acc;
    __syncthreads();
    if (threadIdx.x == 0) {
        const float s = part[0] + part[1] + part[2] + part[3];
        atomicAdd(out, s * (1.0f / 8192.0f));
    }
}

extern "C" void kernel_launch(void* const* d_in, const int* in_sizes, int n_in,
                              void* d_out, int out_size, void* d_ws, size_t ws_size,
                              hipStream_t stream) {
    const float* ue = (const float*)d_in[0];
    const float* ie = (const float*)d_in[1];
    const int*   u  = (const int*)d_in[2];
    const int*   p  = (const int*)d_in[3];
    float* out = (float*)d_out;

    char* ws = (char*)d_ws;
    float* Xf            = (float*)ws;                              // 16 MB: [2][8192][256] f32 (becomes Y)
    unsigned short* Xh   = (unsigned short*)(ws + (16u << 20));     //  8 MB: [2][8192][256] bf16
    unsigned short* Xht  = (unsigned short*)(ws + (24u << 20));     //  8 MB: [2][256][8192] bf16

    k_gather_norm<<<4096, 256, 0, stream>>>(ue, ie, u, p, Xf, Xh, out);
    k_transpose <<<1024, 256, 0, stream>>>(Xh, Xht);
    k_flash     <<<256, 512, 0, stream>>>(Xh, Xht, Xf);
    k_loss      <<<256, 256, 0, stream>>>(Xf, Xf + (size_t)B_ROWS * D_DIM, out);
}

// Round 8
// 417.802 us; speedup vs baseline: 1.0870x; 1.0048x over previous
//
#include <hip/hip_runtime.h>
#include <hip/hip_bf16.h>

#define B_ROWS 8192
#define D_DIM  256
#define KB     64
#define ALPHA  0.8f
// TAU * log2(e) = 3.0 * 1.4426950408889634
#define TAU_LOG2E 4.328085122666890f

typedef __attribute__((ext_vector_type(8))) short bf16x8;
typedef __attribute__((ext_vector_type(4))) float f32x4;
typedef __attribute__((ext_vector_type(4))) unsigned short ushort4v;

__device__ inline unsigned short f2bf(float f) {
    unsigned int u = __builtin_bit_cast(unsigned int, f);
    u += 0x7FFF + ((u >> 16) & 1);   // RNE (finite values)
    return (unsigned short)(u >> 16);
}

// global -> LDS DMA, 16B per lane. LDS dest = wave-uniform base + lane*16
// (linear); the swizzle is applied to the per-lane GLOBAL source instead.
__device__ inline void gl_lds16(const void* g, void* l) {
    __builtin_amdgcn_global_load_lds(
        (const __attribute__((address_space(1))) unsigned int*)g,
        (__attribute__((address_space(3))) unsigned int*)l, 16, 0, 0);
}

// raw barrier that drains only LDS ops (DMA prefetch stays in flight)
__device__ inline void barrier_lgkm() {
    asm volatile("s_waitcnt lgkmcnt(0)" ::: "memory");
    __builtin_amdgcn_s_barrier();
    asm volatile("" ::: "memory");
}
// barrier: staging DMAs + LDS ops complete
__device__ inline void barrier_all() {
    asm volatile("s_waitcnt vmcnt(0) lgkmcnt(0)" ::: "memory");
    __builtin_amdgcn_s_barrier();
    asm volatile("" ::: "memory");
}

// ---------------- Kernel A: gather + row-normalize, emit f32 + bf16 copies --
__global__ __launch_bounds__(256) void k_gather_norm(
    const float* __restrict__ ue, const float* __restrict__ ie,
    const int* __restrict__ u, const int* __restrict__ p,
    float* __restrict__ Xf, unsigned short* __restrict__ Xh,
    float* __restrict__ out)
{
    const int b = blockIdx.x * 4 + (threadIdx.x >> 6);   // 0..16383
    const int lane = threadIdx.x & 63;
    if (b == 0 && lane == 0) out[0] = 0.0f;   // init accumulator (d_out is poisoned)
    const int m = b >> 13;
    const int r = b & 8191;
    const float* src = (m == 0) ? (ue + (size_t)u[r] * D_DIM)
                                : (ie + (size_t)p[r] * D_DIM);
    float4 v = ((const float4*)src)[lane];
    float ss = v.x*v.x + v.y*v.y + v.z*v.z + v.w*v.w;
    #pragma unroll
    for (int mask = 32; mask; mask >>= 1) ss += __shfl_xor(ss, mask);
    const float inv = 1.0f / sqrtf(ss);
    v.x *= inv; v.y *= inv; v.z *= inv; v.w *= inv;
    const size_t off = (size_t)(m * B_ROWS + r) * D_DIM + lane * 4;
    *(float4*)(Xf + off) = v;
    ushort4v h = { f2bf(v.x), f2bf(v.y), f2bf(v.z), f2bf(v.w) };
    *(ushort4v*)(Xh + off) = h;
}

// ---------------- Kernel T: bf16 transpose [2][8192][256] -> [2][256][8192] --
__global__ __launch_bounds__(256) void k_transpose(
    const unsigned short* __restrict__ Xh, unsigned short* __restrict__ Xht)
{
    __shared__ unsigned short tile[64 * 84];
    const int bid = blockIdx.x;                // 0..1023
    const int m = bid >> 9;
    const int t = bid & 511;
    const int rt = t >> 2, ct = t & 3;
    const int r0 = rt * 64, c0 = ct * 64;
    const int tid = threadIdx.x;
    const unsigned short* src = Xh + (size_t)m * B_ROWS * D_DIM;
    unsigned short* dst = Xht + (size_t)m * D_DIM * B_ROWS;
    #pragma unroll
    for (int ph = 0; ph < 2; ++ph) {
        const int row = ph * 32 + (tid >> 3);
        const int ch = tid & 7;
        const unsigned short* s = src + (size_t)(r0 + row) * D_DIM + c0 + ch * 8;
        ushort4v a = *(const ushort4v*)s;
        ushort4v b = *(const ushort4v*)(s + 4);
        *(ushort4v*)(&tile[row * 84 + ch * 8]) = a;
        *(ushort4v*)(&tile[row * 84 + ch * 8 + 4]) = b;
    }
    __syncthreads();
    #pragma unroll
    for (int ph = 0; ph < 2; ++ph) {
        const int d = ph * 32 + (tid >> 3);
        const int kc = tid & 7;
        ushort4v lo = { tile[(kc*8+0)*84 + d], tile[(kc*8+1)*84 + d],
                        tile[(kc*8+2)*84 + d], tile[(kc*8+3)*84 + d] };
        ushort4v hi = { tile[(kc*8+4)*84 + d], tile[(kc*8+5)*84 + d],
                        tile[(kc*8+6)*84 + d], tile[(kc*8+7)*84 + d] };
        unsigned short* o = dst + (size_t)(c0 + d) * B_ROWS + r0 + kc * 8;
        *(ushort4v*)o = lo;
        *(ushort4v*)(o + 4) = hi;
    }
}

// ============ PRIMARY: QB=128 kv-split partial flash =========================
// grid = 256 blocks: blockIdx.x = m*128 + qb*2 + h  (qb 0..63, h 0..1)
// Per block: Q-tile 128 rows (in regs), kv range [h*4096, +4096), 64 iters.
// 8 waves 2Mx4N: wm=w>>2 (64 q-rows), wn=w&3 (QK 16 kv-cols / PV 64 d-cols).
// Per iter/wave: 64 MFMA vs 24 LDS-reads -> MFMA-dominant pipe mix.
__global__ __launch_bounds__(512, 2) void k_flash_part(
    const unsigned short* __restrict__ Xh,   // [2][8192][256] bf16
    const unsigned short* __restrict__ Xht,  // [2][256][8192] bf16
    float* __restrict__ Opart,               // [256][128][256] f32
    float* __restrict__ lsum_part)           // [256][128] f32
{
    __shared__ unsigned char Kls[2][64 * 512];    // 64KB, 16B-XOR-swizzled rows
    __shared__ unsigned char Vtls[2][256 * 128];  // 64KB: d-major, 64 kv per row
    __shared__ unsigned char Pls[128 * 128];      // 16KB: 128 q-rows x 64 kv bf16
    __shared__ float lsum_sh[4][128];

    const int tid = threadIdx.x;
    const int lane = tid & 63;
    const int w = tid >> 6;
    const int wm = w >> 2;            // 0..1: q-row group (64 rows)
    const int wn = w & 3;             // 0..3
    const int m  = blockIdx.x >> 7;
    const int qb = (blockIdx.x >> 1) & 63;
    const int h  = blockIdx.x & 1;
    const int q0 = qb * 128;
    const int kvbase = h * (B_ROWS / 2);

    const unsigned short* Xm  = Xh  + (size_t)m * B_ROWS * D_DIM;
    const unsigned short* Xtm = Xht + (size_t)m * D_DIM * B_ROWS;

    // ---- Q fragments in registers: rows q0 + wm*64 + mi*16 + (lane&15) ------
    bf16x8 qf[4][8];
    #pragma unroll
    for (int mi = 0; mi < 4; ++mi) {
        const unsigned short* qbp = Xm + (size_t)(q0 + wm*64 + mi*16 + (lane & 15)) * D_DIM
                                       + (lane >> 4) * 8;
        #pragma unroll
        for (int kk = 0; kk < 8; ++kk)
            qf[mi][kk] = *(const bf16x8*)(qbp + kk * 32);
    }

    // ---- DMA staging geometry (proven r4 swizzle) ---------------------------
    const int kchunk0 = w * 4;
    const int krow_l  = (lane >> 5);
    const int kcol16  = lane & 31;
    const int vd_l    = (lane >> 3);
    const int vkc16   = lane & 7;

    // ---- LDS read bases -----------------------------------------------------
    const int brow  = wn * 16 + (lane & 15);          // K row for QK B-frag
    const int bswz  = (brow & 7) << 4;
    const int kqoff = (lane >> 4) * 16;               // k-slot offset

    // ---- prologue: stage tile 0 into buffer 0 -------------------------------
    #pragma unroll
    for (int it = 0; it < 4; ++it) {
        const int chunk = kchunk0 + it;
        const int krow = chunk * 2 + krow_l;
        const int kdch = kcol16 ^ (krow & 7);
        gl_lds16(Xm + (size_t)(kvbase + krow) * D_DIM + kdch * 8, &Kls[0][chunk * 1024]);
        const int vd = chunk * 8 + vd_l;
        const int vkc = vkc16 ^ (vd & 7);
        gl_lds16(Xtm + (size_t)vd * B_ROWS + kvbase + vkc * 8, &Vtls[0][chunk * 1024]);
    }
    barrier_all();

    f32x4 o[4][4];
    #pragma unroll
    for (int mi = 0; mi < 4; ++mi)
        #pragma unroll
        for (int nf = 0; nf < 4; ++nf) o[mi][nf] = (f32x4){0.f, 0.f, 0.f, 0.f};
    float lsum[4][4] = {{0.f,0.f,0.f,0.f},{0.f,0.f,0.f,0.f},
                        {0.f,0.f,0.f,0.f},{0.f,0.f,0.f,0.f}};
    int cur = 0;

    for (int kt = 0; kt < 64; ++kt) {
        const int nxt = cur ^ 1;
        // ---- issue DMA for tile kt+1 (in flight across the P barrier) -------
        if (kt + 1 < 64) {
            const int kvn = kvbase + (kt + 1) * KB;
            #pragma unroll
            for (int it = 0; it < 4; ++it) {
                const int chunk = kchunk0 + it;
                const int krow = chunk * 2 + krow_l;
                const int kdch = kcol16 ^ (krow & 7);
                gl_lds16(Xm + (size_t)(kvn + krow) * D_DIM + kdch * 8,
                         &Kls[nxt][chunk * 1024]);
                const int vd = chunk * 8 + vd_l;
                const int vkc = vkc16 ^ (vd & 7);
                gl_lds16(Xtm + (size_t)vd * B_ROWS + kvn + vkc * 8,
                         &Vtls[nxt][chunk * 1024]);
            }
        }

        // ---- QK^T: S[64 x 16] per wave (Q regs x K LDS, K read once/kk) -----
        f32x4 s0 = {0.f,0.f,0.f,0.f}, s1 = {0.f,0.f,0.f,0.f};
        f32x4 s2 = {0.f,0.f,0.f,0.f}, s3 = {0.f,0.f,0.f,0.f};
        {
            const unsigned char* kbase = &Kls[cur][brow * 512];
            #pragma unroll
            for (int kk = 0; kk < 8; ++kk) {
                bf16x8 bK = *(const bf16x8*)(kbase + ((kk * 64 + kqoff) ^ bswz));
                s0 = __builtin_amdgcn_mfma_f32_16x16x32_bf16(qf[0][kk], bK, s0, 0, 0, 0);
                s1 = __builtin_amdgcn_mfma_f32_16x16x32_bf16(qf[1][kk], bK, s1, 0, 0, 0);
                s2 = __builtin_amdgcn_mfma_f32_16x16x32_bf16(qf[2][kk], bK, s2, 0, 0, 0);
                s3 = __builtin_amdgcn_mfma_f32_16x16x32_bf16(qf[3][kk], bK, s3, 0, 0, 0);
            }
        }
        // ---- P = exp(TAU*S); row-sum partials; bf16 P to LDS ----------------
        #pragma unroll
        for (int i = 0; i < 4; ++i) {
            const float p0 = exp2f(s0[i] * TAU_LOG2E);
            const float p1 = exp2f(s1[i] * TAU_LOG2E);
            const float p2 = exp2f(s2[i] * TAU_LOG2E);
            const float p3 = exp2f(s3[i] * TAU_LOG2E);
            lsum[0][i] += p0;  lsum[1][i] += p1;
            lsum[2][i] += p2;  lsum[3][i] += p3;
            const int prb = wm*64 + (lane >> 4) * 4 + i;
            const int pc2 = (wn*16 + (lane & 15)) * 2;
            *(unsigned short*)(Pls + (prb   )*128 + (pc2 ^ (((prb   ) & 7) << 4))) = f2bf(p0);
            *(unsigned short*)(Pls + (prb+16)*128 + (pc2 ^ (((prb+16) & 7) << 4))) = f2bf(p1);
            *(unsigned short*)(Pls + (prb+32)*128 + (pc2 ^ (((prb+32) & 7) << 4))) = f2bf(p2);
            *(unsigned short*)(Pls + (prb+48)*128 + (pc2 ^ (((prb+48) & 7) << 4))) = f2bf(p3);
        }
        barrier_lgkm();   // P visible; prefetch DMAs NOT drained

        // ---- PV: O[64 x 64] += P[64 x 64] @ V[64 x 64-d-slice] --------------
        #pragma unroll
        for (int ks = 0; ks < 2; ++ks) {
            bf16x8 aP[4];
            #pragma unroll
            for (int mi = 0; mi < 4; ++mi) {
                const int ar = wm*64 + mi*16 + (lane & 15);
                aP[mi] = *(const bf16x8*)(Pls + ar*128 + ((ks*64 + kqoff) ^ ((ar & 7) << 4)));
            }
            #pragma unroll
            for (int nf = 0; nf < 4; ++nf) {
                const int dr = wn*64 + nf*16 + (lane & 15);
                bf16x8 bV = *(const bf16x8*)(&Vtls[cur][dr*128 + ((ks*64 + kqoff) ^ ((dr & 7) << 4))]);
                o[0][nf] = __builtin_amdgcn_mfma_f32_16x16x32_bf16(aP[0], bV, o[0][nf], 0, 0, 0);
                o[1][nf] = __builtin_amdgcn_mfma_f32_16x16x32_bf16(aP[1], bV, o[1][nf], 0, 0, 0);
                o[2][nf] = __builtin_amdgcn_mfma_f32_16x16x32_bf16(aP[2], bV, o[2][nf], 0, 0, 0);
                o[3][nf] = __builtin_amdgcn_mfma_f32_16x16x32_bf16(aP[3], bV, o[3][nf], 0, 0, 0);
            }
        }

        barrier_all();    // DMAs landed; all LDS reads of cur/P complete
        cur = nxt;
    }

    // ---- epilogue: partial row-sums + partial O to workspace ----------------
    #pragma unroll
    for (int mi = 0; mi < 4; ++mi)
        #pragma unroll
        for (int i = 0; i < 4; ++i) {
            float v = lsum[mi][i];
            v += __shfl_xor(v, 1); v += __shfl_xor(v, 2);
            v += __shfl_xor(v, 4); v += __shfl_xor(v, 8);
            if ((lane & 15) == 0)
                lsum_sh[wn][wm*64 + mi*16 + (lane >> 4)*4 + i] = v;
        }
    __syncthreads();
    if (tid < 128)
        lsum_part[(size_t)blockIdx.x * 128 + tid] =
            lsum_sh[0][tid] + lsum_sh[1][tid] + lsum_sh[2][tid] + lsum_sh[3][tid];

    float* Ob = Opart + (size_t)blockIdx.x * 128 * D_DIM;
    #pragma unroll
    for (int mi = 0; mi < 4; ++mi)
        #pragma unroll
        for (int nf = 0; nf < 4; ++nf)
            #pragma unroll
            for (int i = 0; i < 4; ++i) {
                const int row = wm*64 + mi*16 + (lane >> 4)*4 + i;
                const int col = wn*64 + nf*16 + (lane & 15);
                Ob[row * D_DIM + col] = o[mi][nf][i];
            }
}

// ---- combine halves + spec-smooth epilogue + loss, fused --------------------
// grid = 2048 blocks x 256 thr (4 waves); wave handles one row r (both m).
__global__ __launch_bounds__(256) void k_combine_loss(
    const float* __restrict__ Xf, const float* __restrict__ Opart,
    const float* __restrict__ lsum_part, float* __restrict__ out)
{
    __shared__ float part[4];
    const int w = threadIdx.x >> 6;
    const int lane = threadIdx.x & 63;
    const int r = blockIdx.x * 4 + w;
    const int qb = r >> 7, ri = r & 127;

    float y[2][4];
    float nrm[2];
    #pragma unroll
    for (int m = 0; m < 2; ++m) {
        const int blk0 = m * 128 + qb * 2;
        const float l = lsum_part[(size_t)blk0 * 128 + ri]
                      + lsum_part[(size_t)(blk0 + 1) * 128 + ri];
        const float c = ALPHA / l;
        const float4 x  = *(const float4*)(Xf + ((size_t)m * B_ROWS + r) * D_DIM + lane * 4);
        const float4 o0 = *(const float4*)(Opart + ((size_t)blk0 * 128 + ri) * D_DIM + lane * 4);
        const float4 o1 = *(const float4*)(Opart + ((size_t)(blk0 + 1) * 128 + ri) * D_DIM + lane * 4);
        y[m][0] = x.x - c * (o0.x + o1.x);
        y[m][1] = x.y - c * (o0.y + o1.y);
        y[m][2] = x.z - c * (o0.z + o1.z);
        y[m][3] = x.w - c * (o0.w + o1.w);
        float s = y[m][0]*y[m][0] + y[m][1]*y[m][1] + y[m][2]*y[m][2] + y[m][3]*y[m][3];
        #pragma unroll
        for (int mask = 32; mask; mask >>= 1) s += __shfl_xor(s, mask);
        nrm[m] = s;
    }
    float d = y[0][0]*y[1][0] + y[0][1]*y[1][1] + y[0][2]*y[1][2] + y[0][3]*y[1][3];
    #pragma unroll
    for (int mask = 32; mask; mask >>= 1) d += __shfl_xor(d, mask);
    if (lane == 0) {
        // yhat = y * ||y|| (SHRINK_NORM=1) => dot = ||yu||*||yp||*sum(yu.yp)
        const float z = sqrtf(nrm[0] * nrm[1]) * d;
        part[w] = log1pf(expf(-z));
    }
    __syncthreads();
    if (threadIdx.x == 0)
        atomicAdd(out, (part[0] + part[1] + part[2] + part[3]) * (1.0f / 8192.0f));
}

// ============ FALLBACK PATH (exact round-4 kernels, ws too small) ============
__global__ __launch_bounds__(512, 2) void k_flash(
    const unsigned short* __restrict__ Xh, const unsigned short* __restrict__ Xht,
    float* __restrict__ Xf)
{
    __shared__ unsigned char Kls[2][64 * 512];
    __shared__ unsigned char Vtls[2][256 * 128];
    __shared__ unsigned char Pls[64 * 128];
    __shared__ float lsum_sh[4][64];
    __shared__ float nrm_sh[4][64];

    const int tid = threadIdx.x;
    const int lane = tid & 63;
    const int w = tid >> 6;
    const int wm = w >> 2;
    const int wn = w & 3;
    const int m = blockIdx.x >> 7;
    const int q0 = (blockIdx.x & 127) * 64;

    const unsigned short* Xm  = Xh  + (size_t)m * B_ROWS * D_DIM;
    const unsigned short* Xtm = Xht + (size_t)m * D_DIM * B_ROWS;
    float* Xfm = Xf + (size_t)m * B_ROWS * D_DIM;

    bf16x8 qf[2][8];
    #pragma unroll
    for (int mi = 0; mi < 2; ++mi) {
        const unsigned short* qbp = Xm + (size_t)(q0 + wm*32 + mi*16 + (lane & 15)) * D_DIM
                                       + (lane >> 4) * 8;
        #pragma unroll
        for (int kk = 0; kk < 8; ++kk)
            qf[mi][kk] = *(const bf16x8*)(qbp + kk * 32);
    }

    const int kchunk0 = w * 4;
    const int krow_l  = (lane >> 5);
    const int kcol16  = lane & 31;
    const int vd_l    = (lane >> 3);
    const int vkc16   = lane & 7;

    #pragma unroll
    for (int it = 0; it < 4; ++it) {
        const int chunk = kchunk0 + it;
        const int krow = chunk * 2 + krow_l;
        const int kdch = kcol16 ^ (krow & 7);
        gl_lds16(Xm + (size_t)krow * D_DIM + kdch * 8, &Kls[0][chunk * 1024]);
        const int vd = chunk * 8 + vd_l;
        const int vkc = vkc16 ^ (vd & 7);
        gl_lds16(Xtm + (size_t)vd * B_ROWS + vkc * 8, &Vtls[0][chunk * 1024]);
    }
    barrier_all();

    f32x4 o[2][4];
    #pragma unroll
    for (int mi = 0; mi < 2; ++mi)
        #pragma unroll
        for (int nf = 0; nf < 4; ++nf) o[mi][nf] = (f32x4){0.f, 0.f, 0.f, 0.f};
    float lsum[2][4] = {{0.f,0.f,0.f,0.f},{0.f,0.f,0.f,0.f}};
    int cur = 0;

    for (int kt = 0; kt < 128; ++kt) {
        const int nxt = cur ^ 1;
        if (kt + 1 < 128) {
            const int kvn = (kt + 1) * KB;
            #pragma unroll
            for (int it = 0; it < 4; ++it) {
                const int chunk = kchunk0 + it;
                const int krow = chunk * 2 + krow_l;
                const int kdch = kcol16 ^ (krow & 7);
                gl_lds16(Xm + (size_t)(kvn + krow) * D_DIM + kdch * 8, &Kls[nxt][chunk * 1024]);
                const int vd = chunk * 8 + vd_l;
                const int vkc = vkc16 ^ (vd & 7);
                gl_lds16(Xtm + (size_t)vd * B_ROWS + kvn + vkc * 8, &Vtls[nxt][chunk * 1024]);
            }
        }
        f32x4 s0 = {0.f,0.f,0.f,0.f}, s1 = {0.f,0.f,0.f,0.f};
        {
            const int brow = wn * 16 + (lane & 15);
            const unsigned char* kbase = &Kls[cur][brow * 512];
            const int bswz = (brow & 7) << 4;
            #pragma unroll
            for (int kk = 0; kk < 8; ++kk) {
                const int kb = kk * 64 + ((lane >> 4) * 16);
                bf16x8 bK = *(const bf16x8*)(kbase + (kb ^ bswz));
                s0 = __builtin_amdgcn_mfma_f32_16x16x32_bf16(qf[0][kk], bK, s0, 0, 0, 0);
                s1 = __builtin_amdgcn_mfma_f32_16x16x32_bf16(qf[1][kk], bK, s1, 0, 0, 0);
            }
        }
        #pragma unroll
        for (int i = 0; i < 4; ++i) {
            const float p0 = exp2f(s0[i] * TAU_LOG2E);
            const float p1 = exp2f(s1[i] * TAU_LOG2E);
            lsum[0][i] += p0;
            lsum[1][i] += p1;
            const int pr0 = wm*32 + (lane >> 4) * 4 + i;
            const int pr1 = pr0 + 16;
            const int pc2 = (wn*16 + (lane & 15)) * 2;
            *(unsigned short*)(Pls + pr0*128 + (pc2 ^ ((pr0 & 7) << 4))) = f2bf(p0);
            *(unsigned short*)(Pls + pr1*128 + (pc2 ^ ((pr1 & 7) << 4))) = f2bf(p1);
        }
        barrier_lgkm();
        bf16x8 aP[2][2];
        #pragma unroll
        for (int mi = 0; mi < 2; ++mi)
            #pragma unroll
            for (int ks = 0; ks < 2; ++ks) {
                const int ar = wm*32 + mi*16 + (lane & 15);
                const int akb = ks*64 + ((lane >> 4) * 16);
                aP[mi][ks] = *(const bf16x8*)(Pls + ar*128 + (akb ^ ((ar & 7) << 4)));
            }
        #pragma unroll
        for (int ks = 0; ks < 2; ++ks) {
            #pragma unroll
            for (int nf = 0; nf < 4; ++nf) {
                const int dr = wn*64 + nf*16 + (lane & 15);
                const int kb2 = ks*64 + ((lane >> 4) * 16);
                bf16x8 bV = *(const bf16x8*)(&Vtls[cur][dr*128 + (kb2 ^ ((dr & 7) << 4))]);
                o[0][nf] = __builtin_amdgcn_mfma_f32_16x16x32_bf16(aP[0][ks], bV, o[0][nf], 0, 0, 0);
                o[1][nf] = __builtin_amdgcn_mfma_f32_16x16x32_bf16(aP[1][ks], bV, o[1][nf], 0, 0, 0);
            }
        }
        barrier_all();
        cur = nxt;
    }

    #pragma unroll
    for (int mi = 0; mi < 2; ++mi)
        #pragma unroll
        for (int i = 0; i < 4; ++i) {
            float v = lsum[mi][i];
            v += __shfl_xor(v, 1); v += __shfl_xor(v, 2);
            v += __shfl_xor(v, 4); v += __shfl_xor(v, 8);
            if ((lane & 15) == 0)
                lsum_sh[wn][wm*32 + mi*16 + (lane >> 4)*4 + i] = v;
        }
    __syncthreads();

    float nrm[2][4] = {{0.f,0.f,0.f,0.f},{0.f,0.f,0.f,0.f}};
    #pragma unroll
    for (int mi = 0; mi < 2; ++mi)
        #pragma unroll
        for (int nf = 0; nf < 4; ++nf)
            #pragma unroll
            for (int i = 0; i < 4; ++i) {
                const int row = wm*32 + mi*16 + (lane >> 4)*4 + i;
                const int col = wn*64 + nf*16 + (lane & 15);
                const float x = Xfm[(size_t)(q0 + row) * D_DIM + col];
                const float lt = lsum_sh[0][row] + lsum_sh[1][row]
                               + lsum_sh[2][row] + lsum_sh[3][row];
                const float yv = x - (ALPHA / lt) * o[mi][nf][i];
                o[mi][nf][i] = yv;
                nrm[mi][i] += yv * yv;
            }
    #pragma unroll
    for (int mi = 0; mi < 2; ++mi)
        #pragma unroll
        for (int i = 0; i < 4; ++i) {
            float v = nrm[mi][i];
            v += __shfl_xor(v, 1); v += __shfl_xor(v, 2);
            v += __shfl_xor(v, 4); v += __shfl_xor(v, 8);
            if ((lane & 15) == 0)
                nrm_sh[wn][wm*32 + mi*16 + (lane >> 4)*4 + i] = v;
        }
    __syncthreads();
    #pragma unroll
    for (int mi = 0; mi < 2; ++mi)
        #pragma unroll
        for (int nf = 0; nf < 4; ++nf)
            #pragma unroll
            for (int i = 0; i < 4; ++i) {
                const int row = wm*32 + mi*16 + (lane >> 4)*4 + i;
                const int col = wn*64 + nf*16 + (lane & 15);
                const float scale = sqrtf(nrm_sh[0][row] + nrm_sh[1][row]
                                        + nrm_sh[2][row] + nrm_sh[3][row]);
                Xfm[(size_t)(q0 + row) * D_DIM + col] = o[mi][nf][i] * scale;
            }
}

__global__ __launch_bounds__(256) void k_loss(
    const float* __restrict__ Yu, const float* __restrict__ Yp,
    float* __restrict__ out)
{
    __shared__ float part[4];
    const int w = threadIdx.x >> 6;
    const int lane = threadIdx.x & 63;
    float acc = 0.0f;
    #pragma unroll
    for (int r = 0; r < 8; ++r) {
        const int row = blockIdx.x * 32 + w * 8 + r;
        const float4 a = *(const float4*)(Yu + (size_t)row * D_DIM + lane * 4);
        const float4 b = *(const float4*)(Yp + (size_t)row * D_DIM + lane * 4);
        float dot = a.x*b.x + a.y*b.y + a.z*b.z + a.w*b.w;
        #pragma unroll
        for (int mask = 32; mask; mask >>= 1) dot += __shfl_xor(dot, mask);
        if (lane == 0) acc += log1pf(expf(-dot));
    }
    if (lane == 0) part[w] = acc;
    __syncthreads();
    if (threadIdx.x == 0) {
        const float s = part[0] + part[1] + part[2] + part[3];
        atomicAdd(out, s * (1.0f / 8192.0f));
    }
}

extern "C" void kernel_launch(void* const* d_in, const int* in_sizes, int n_in,
                              void* d_out, int out_size, void* d_ws, size_t ws_size,
                              hipStream_t stream) {
    const float* ue = (const float*)d_in[0];
    const float* ie = (const float*)d_in[1];
    const int*   u  = (const int*)d_in[2];
    const int*   p  = (const int*)d_in[3];
    float* out = (float*)d_out;

    char* ws = (char*)d_ws;
    float* Xf            = (float*)ws;                              // 16 MB
    unsigned short* Xh   = (unsigned short*)(ws + (16u << 20));     //  8 MB
    unsigned short* Xht  = (unsigned short*)(ws + (24u << 20));     //  8 MB
    float* Opart         = (float*)(ws + (32u << 20));              // 32 MB: [256][128][256]
    float* lsum_part     = (float*)(ws + (64u << 20));              // 128 KB

    const size_t need = (64u << 20) + (128u << 10);

    k_gather_norm<<<4096, 256, 0, stream>>>(ue, ie, u, p, Xf, Xh, out);
    k_transpose <<<1024, 256, 0, stream>>>(Xh, Xht);
    if (ws_size >= need) {
        k_flash_part  <<<256, 512, 0, stream>>>(Xh, Xht, Opart, lsum_part);
        k_combine_loss<<<2048, 256, 0, stream>>>(Xf, Opart, lsum_part, out);
    } else {
        k_flash<<<256, 512, 0, stream>>>(Xh, Xht, Xf);
        k_loss <<<256, 256, 0, stream>>>(Xf, Xf + (size_t)B_ROWS * D_DIM, out);
    }
}